// Round 4
// baseline (807.235 us; speedup 1.0000x reference)
//
#include <hip/hip_runtime.h>
#include <cstddef>
#include <cstdint>

// ---------------- problem constants ----------------
#define B_SZ    2
#define SEQ     2048
#define DMODEL  2048
#define DINNER  4096
#define DSTATE  128
#define NHEADS  64
#define HEADDIM 64
#define DXBC    4352          // DINNER + 2*DSTATE
#define NPROJ   8448          // DINNER + DXBC (z | xBC); dt handled separately in fp32
#define CHUNK   64
#define NCHUNK  32
#define TOKENS  (B_SZ*SEQ)    // 4096

typedef __attribute__((ext_vector_type(8))) short short8;   // 8 x bf16
typedef __attribute__((ext_vector_type(4))) float floatx4;

// ---- bf16 <-> f32 helpers ----
__device__ inline float us2f(unsigned short u) {
  union { uint32_t i; float f; } c; c.i = ((uint32_t)u) << 16; return c.f;
}
__device__ inline unsigned short f2us(float f) {
  union { float f; uint32_t i; } c; c.f = f;
  uint32_t r = (c.i + 0x7fffu + ((c.i >> 16) & 1u)) >> 16;
  return (unsigned short)r;
}
__device__ inline float plo(uint32_t v) {
  union { uint32_t i; float f; } c; c.i = v << 16; return c.f;
}
__device__ inline float phi(uint32_t v) {
  union { uint32_t i; float f; } c; c.i = v & 0xffff0000u; return c.f;
}

// ---------------- f32 -> bf16 cast (vectorized) ----------------
__global__ __launch_bounds__(256) void cast_f32_bf16(
    const float* __restrict__ src, unsigned short* __restrict__ dst, int n) {
  int i = (blockIdx.x * 256 + threadIdx.x) * 4;
  if (i < n) {
    float4 v = *(const float4*)(src + i);
    ushort4 o;
    o.x = f2us(v.x); o.y = f2us(v.y); o.z = f2us(v.z); o.w = f2us(v.w);
    *(ushort4*)(dst + i) = o;
  }
}

// ======= pipelined MFMA bf16 NT GEMM: C[M,N] = A[M,K] @ B[N,K]^T ============
// BM=128, BN=256, 256 threads (4 waves, 1M x 4N), per-wave out 128x64.
// K advanced in 32-wide halves. LDS = ring of 3 half-buffers (24KB each:
// A 128x32 | B 256x32) -> 72KB -> 2 blocks/CU. Depth-2 prefetch, counted
// vmcnt(6) (never 0 mid-loop).
// R4 change (m196/m201 fine-interleave): each 32-K step is split into TWO
// 16-MFMA phases, each {ds_read subtile | stage 3 loads -> s_barrier ->
// lgkmcnt(0) -> setprio(1) 16 MFMA setprio(0) -> s_barrier}. Barrier density
// 1 per 8 K (m201-equivalent), loads span phases via counted vmcnt.
// Bank swizzle for 64B rows: 16B-slot ^= (row>>1)&3, applied both-sides.
// XCD-aware bijective blockIdx remap (nwg % 8 == 0 for both call sites).
template<int OUT_BF16>
__global__ __launch_bounds__(256, 2) void gemm_bt_p3(
    const unsigned short* __restrict__ A, const unsigned short* __restrict__ B,
    void* __restrict__ Cout, int M, int N, int K, int GM) {
  __shared__ __align__(16) unsigned short sT[3 * 12288];  // 3 x (A 4096 | B 8192)
  const int tid  = threadIdx.x;
  const int lane = tid & 63;
  const int wc   = tid >> 6;        // wave 0..3 = N quadrant
  const int fr   = lane & 15;
  const int fq   = lane >> 4;

  const int nwg  = gridDim.x;
  int wgid = blockIdx.x;
  if ((nwg & 7) == 0) wgid = (wgid & 7) * (nwg >> 3) + (wgid >> 3);
  const int bm = (wgid % GM) * 128;
  const int bn = (wgid / GM) * 256;

  floatx4 acc[8][4];
  #pragma unroll
  for (int i = 0; i < 8; ++i)
    #pragma unroll
    for (int j = 0; j < 4; ++j) acc[i][j] = (floatx4){0.f, 0.f, 0.f, 0.f};

  // stage one slice (3 of 6 chunks) of a 32-wide half-K into ring buffer rb.
  // chunks 0..1 = A (128 rows x 4 slots), 2..5 = B (256 rows x 4 slots).
  auto stage3 = [&](int rb, int kb, int half) {
    unsigned short* dst = (unsigned short*)sT + rb * 12288;
    #pragma unroll
    for (int qq = 0; qq < 3; ++qq) {
      int q = half * 3 + qq;
      if (q < 2) {
        int i = q * 256 + tid;
        int row = i >> 2, slot = i & 3;
        const unsigned short* g =
            A + (size_t)(bm + row) * K + kb + 8 * (slot ^ ((row >> 1) & 3));
        __builtin_amdgcn_global_load_lds(
            (const __attribute__((address_space(1))) uint32_t*)g,
            (__attribute__((address_space(3))) uint32_t*)(dst + i * 8), 16, 0, 0);
      } else {
        int i = (q - 2) * 256 + tid;
        int row = i >> 2, slot = i & 3;
        const unsigned short* g =
            B + (size_t)(bn + row) * K + kb + 8 * (slot ^ ((row >> 1) & 3));
        __builtin_amdgcn_global_load_lds(
            (const __attribute__((address_space(1))) uint32_t*)g,
            (__attribute__((address_space(3))) uint32_t*)(dst + 4096 + i * 8), 16, 0, 0);
      }
    }
  };

  const int NH = K >> 5;
  // prologue: halves 0,1 in flight; wait for half 0 only.
  stage3(0, 0, 0); stage3(0, 0, 1);
  stage3(1, 32, 0); stage3(1, 32, 1);
  asm volatile("s_waitcnt vmcnt(6)" ::: "memory");
  asm volatile("s_barrier" ::: "memory");

  int cb = 0, sb = 2;   // current ring idx, stage ring idx (h+2)
  for (int h = 0; h < NH; ++h) {
    const unsigned short* buf = (const unsigned short*)sT + cb * 12288;
    const int k2 = (h + 2) << 5;
    const bool pre = (h + 2 < NH);

    short8 af[8], bf[4];
    // ---------------- phase 0: i-tiles 0..3 ----------------
    #pragma unroll
    for (int i = 0; i < 4; ++i) {
      int row = i * 16 + fr;
      af[i] = *(const short8*)(buf + row * 32 + 8 * (fq ^ ((row >> 1) & 3)));
    }
    #pragma unroll
    for (int j = 0; j < 4; ++j) {
      int row = wc * 64 + j * 16 + fr;
      bf[j] = *(const short8*)(buf + 4096 + row * 32 + 8 * (fq ^ ((row >> 1) & 3)));
    }
    if (pre) stage3(sb, k2, 0);
    asm volatile("s_barrier" ::: "memory");
    asm volatile("s_waitcnt lgkmcnt(0)" ::: "memory");
    __builtin_amdgcn_s_setprio(1);
    #pragma unroll
    for (int i = 0; i < 4; ++i)
      #pragma unroll
      for (int j = 0; j < 4; ++j)
        acc[i][j] = __builtin_amdgcn_mfma_f32_16x16x32_bf16(af[i], bf[j], acc[i][j], 0, 0, 0);
    __builtin_amdgcn_s_setprio(0);
    asm volatile("s_barrier" ::: "memory");

    // ---------------- phase 1: i-tiles 4..7 ----------------
    #pragma unroll
    for (int i = 4; i < 8; ++i) {
      int row = i * 16 + fr;
      af[i] = *(const short8*)(buf + row * 32 + 8 * (fq ^ ((row >> 1) & 3)));
    }
    if (pre) stage3(sb, k2, 1);
    if (h < NH - 2) asm volatile("s_waitcnt vmcnt(6)" ::: "memory");
    else            asm volatile("s_waitcnt vmcnt(0)" ::: "memory");
    asm volatile("s_barrier" ::: "memory");
    asm volatile("s_waitcnt lgkmcnt(0)" ::: "memory");
    __builtin_amdgcn_s_setprio(1);
    #pragma unroll
    for (int i = 4; i < 8; ++i)
      #pragma unroll
      for (int j = 0; j < 4; ++j)
        acc[i][j] = __builtin_amdgcn_mfma_f32_16x16x32_bf16(af[i], bf[j], acc[i][j], 0, 0, 0);
    __builtin_amdgcn_s_setprio(0);
    asm volatile("s_barrier" ::: "memory");

    cb = (cb == 2) ? 0 : cb + 1;
    sb = (sb == 2) ? 0 : sb + 1;
  }

  // epilogue
  #pragma unroll
  for (int i = 0; i < 8; ++i) {
    #pragma unroll
    for (int j = 0; j < 4; ++j) {
      int col = bn + wc * 64 + j * 16 + fr;
      #pragma unroll
      for (int r = 0; r < 4; ++r) {
        int row = bm + i * 16 + fq * 4 + r;
        if (OUT_BF16)
          ((unsigned short*)Cout)[(size_t)row * N + col] = f2us(acc[i][j][r]);
        else
          ((float*)Cout)[(size_t)row * N + col] = acc[i][j][r];
      }
    }
  }
}

// ---------------- fp32 tiled NT GEMM (fallback path only) ----------------
__device__ inline void loadA4(const float* p, float* d) {
  float4 v = *(const float4*)p; d[0]=v.x; d[1]=v.y; d[2]=v.z; d[3]=v.w;
}
__device__ inline void loadA4(const unsigned short* p, float* d) {
  ushort4 v = *(const ushort4*)p;
  d[0]=us2f(v.x); d[1]=us2f(v.y); d[2]=us2f(v.z); d[3]=us2f(v.w);
}
__device__ inline void store8(float* C, size_t off, const float* v) {
  *(float4*)(C + off)     = make_float4(v[0], v[1], v[2], v[3]);
  *(float4*)(C + off + 4) = make_float4(v[4], v[5], v[6], v[7]);
}
__device__ inline void store8(unsigned short* C, size_t off, const float* v) {
  ushort4 a; a.x=f2us(v[0]); a.y=f2us(v[1]); a.z=f2us(v[2]); a.w=f2us(v[3]);
  ushort4 b; b.x=f2us(v[4]); b.y=f2us(v[5]); b.z=f2us(v[6]); b.w=f2us(v[7]);
  *(ushort4*)(C + off) = a; *(ushort4*)(C + off + 4) = b;
}

template<typename AT, typename OT>
__global__ __launch_bounds__(256) void gemm_nt(
    const AT* __restrict__ A, const float* __restrict__ Bw,
    OT* __restrict__ C, int M, int N, int K) {
  __shared__ float As[16][128+4];
  __shared__ float Bs[16][128+4];
  const int bm = blockIdx.y * 128;
  const int bn = blockIdx.x * 128;
  const int tid = threadIdx.x;
  const int tx = tid & 15, ty = tid >> 4;

  float acc[8][8];
  #pragma unroll
  for (int i = 0; i < 8; ++i)
    #pragma unroll
    for (int j = 0; j < 8; ++j) acc[i][j] = 0.f;

  for (int k0 = 0; k0 < K; k0 += 16) {
    #pragma unroll
    for (int r = 0; r < 2; ++r) {
      int i = tid + r * 256;
      int m  = i >> 2;
      int kv = (i & 3) << 2;
      float va[4];
      loadA4(A + (size_t)(bm + m) * K + k0 + kv, va);
      As[kv+0][m] = va[0]; As[kv+1][m] = va[1]; As[kv+2][m] = va[2]; As[kv+3][m] = va[3];
      float vb[4] = {0.f, 0.f, 0.f, 0.f};
      if (bn + m < N) loadA4(Bw + (size_t)(bn + m) * K + k0 + kv, vb);
      Bs[kv+0][m] = vb[0]; Bs[kv+1][m] = vb[1]; Bs[kv+2][m] = vb[2]; Bs[kv+3][m] = vb[3];
    }
    __syncthreads();
    #pragma unroll
    for (int kk = 0; kk < 16; ++kk) {
      float ra[8], rb[8];
      *(float4*)&ra[0] = *(const float4*)&As[kk][ty*8];
      *(float4*)&ra[4] = *(const float4*)&As[kk][ty*8+4];
      *(float4*)&rb[0] = *(const float4*)&Bs[kk][tx*8];
      *(float4*)&rb[4] = *(const float4*)&Bs[kk][tx*8+4];
      #pragma unroll
      for (int i = 0; i < 8; ++i)
        #pragma unroll
        for (int j = 0; j < 8; ++j) acc[i][j] += ra[i] * rb[j];
    }
    __syncthreads();
  }
  #pragma unroll
  for (int i = 0; i < 8; ++i) {
    int m  = bm + ty*8 + i;
    int n0 = bn + tx*8;
    if (n0 < N) store8(C, (size_t)m * N + n0, &acc[i][0]);
  }
}

// ---------------- dt GEMM (fp32, tiled) ----------------
__global__ __launch_bounds__(256) void dt_gemm(
    const float* __restrict__ x, const float* __restrict__ W,
    float* __restrict__ dtr) {
  __shared__ float sX[32][64];   // [kk][token]
  __shared__ float sW[32][64];   // [kk][head]
  const int tid = threadIdx.x;
  const int t0 = blockIdx.x * 64;
  const int tx = tid & 15;
  const int ty = tid >> 4;
  const float* Wdt = W + (size_t)NPROJ * DMODEL;

  float acc[4][4];
  #pragma unroll
  for (int i = 0; i < 4; ++i)
    #pragma unroll
    for (int j = 0; j < 4; ++j) acc[i][j] = 0.f;

  const int r  = tid >> 3;
  const int kq = (tid & 7) * 4;

  for (int k0 = 0; k0 < DMODEL; k0 += 32) {
    __syncthreads();
    #pragma unroll
    for (int rr = 0; rr < 2; ++rr) {
      int t = r + rr * 32;
      float4 v = *(const float4*)(x + (size_t)(t0 + t) * DMODEL + k0 + kq);
      sX[kq+0][t] = v.x; sX[kq+1][t] = v.y; sX[kq+2][t] = v.z; sX[kq+3][t] = v.w;
    }
    #pragma unroll
    for (int rr = 0; rr < 2; ++rr) {
      int hh = r + rr * 32;
      float4 v = *(const float4*)(Wdt + (size_t)hh * DMODEL + k0 + kq);
      sW[kq+0][hh] = v.x; sW[kq+1][hh] = v.y; sW[kq+2][hh] = v.z; sW[kq+3][hh] = v.w;
    }
    __syncthreads();
    #pragma unroll
    for (int kk = 0; kk < 32; ++kk) {
      float4 ra = *(const float4*)&sX[kk][ty*4];
      float4 rb = *(const float4*)&sW[kk][tx*4];
      float a[4] = {ra.x, ra.y, ra.z, ra.w};
      float b[4] = {rb.x, rb.y, rb.z, rb.w};
      #pragma unroll
      for (int i = 0; i < 4; ++i)
        #pragma unroll
        for (int j = 0; j < 4; ++j)
          acc[i][j] += a[i] * b[j];
    }
  }
  #pragma unroll
  for (int i = 0; i < 4; ++i) {
    float4 o = make_float4(acc[i][0], acc[i][1], acc[i][2], acc[i][3]);
    *(float4*)(dtr + (size_t)(t0 + ty*4 + i) * NHEADS + tx*4) = o;
  }
}

// ================= split-scan path =================
__global__ __launch_bounds__(256) void bc_conv_g(
    const unsigned short* __restrict__ proj, const float* __restrict__ cw,
    const float* __restrict__ cb, unsigned short* __restrict__ bcact,
    float* __restrict__ gbuf) {
  const int c = blockIdx.x & 31;
  const int b = blockIdx.x >> 5;
  const int tid = threadIdx.x;
  const int t0 = b * SEQ + c * CHUNK;
  __shared__ unsigned short sB[64*130];
  __shared__ unsigned short sC[64*130];
  for (int i = tid; i < 64*256; i += 256) {
    int s = i >> 8, ch = i & 255;
    int cx = 4096 + ch;
    int lb = c * CHUNK + s;
    float acc = cb[cx];
    #pragma unroll
    for (int j = 0; j < 4; ++j) {
      int ll = lb - 3 + j;
      if (ll >= 0)
        acc += cw[cx*4 + j] * us2f(proj[(size_t)(b*SEQ + ll) * NPROJ + DINNER + cx]);
    }
    float v = acc / (1.f + expf(-acc));
    unsigned short uv = f2us(v);
    if (ch < 128) sB[s*130 + ch] = uv;
    else          sC[s*130 + (ch - 128)] = uv;
    bcact[(size_t)(t0 + s) * 256 + ch] = uv;
  }
  __syncthreads();
  const int l = tid >> 2, q = tid & 3;
  float g[16];
  #pragma unroll
  for (int j = 0; j < 16; ++j) g[j] = 0.f;
  const uint32_t* Cu = (const uint32_t*)&sC[l * 130];
  for (int u = 0; u < 64; ++u) {
    uint32_t cv = Cu[u];
    float c0 = plo(cv), c1 = phi(cv);
    #pragma unroll
    for (int j = 0; j < 16; ++j) {
      uint32_t bv = ((const uint32_t*)&sB[(q*16 + j) * 130])[u];
      g[j] += c0 * plo(bv) + c1 * phi(bv);
    }
  }
  float* gr = gbuf + ((size_t)(b*NCHUNK + c)) * 4096 + l*64 + q*16;
  #pragma unroll
  for (int j = 0; j < 16; ++j) gr[j] = g[j];
}

// ---- A2 (MFMA) ----
__global__ __launch_bounds__(256, 4) void ssd_phase_a2_mfma(
    const unsigned short* __restrict__ proj, const unsigned short* __restrict__ bcact,
    const float* __restrict__ dtr, const float* __restrict__ cw,
    const float* __restrict__ cb, const float* __restrict__ A_log,
    const float* __restrict__ dt_bias, const float* __restrict__ gbuf,
    const float* __restrict__ Dv,
    unsigned short* __restrict__ cs, float* __restrict__ acs,
    unsigned short* __restrict__ yscan) {
  const int h = blockIdx.x & 63;
  const int c = (blockIdx.x >> 6) & 31;
  const int b = blockIdx.x >> 11;
  const int tid = threadIdx.x;
  const int t0 = b * SEQ + c * CHUNK;
  const int lane = tid & 63, wave = tid >> 6;
  const int fr = lane & 15, fq = lane >> 4;

  __shared__ __align__(16) unsigned short sBt[128*72];
  __shared__ __align__(16) unsigned short sXh[64*72];
  __shared__ __align__(16) unsigned short sW[64*72];
  __shared__ float sdt[64], sAc[64], sdecay[64];

  const float Ah = -expf(A_log[h]);
  if (tid < 64) {
    float raw = dtr[(size_t)(t0 + tid) * NHEADS + h] + dt_bias[h];
    float dt = (raw > 20.f) ? raw : log1pf(expf(raw));
    sdt[tid] = dt;
    float v = dt * Ah;
    #pragma unroll
    for (int off = 1; off < 64; off <<= 1) {
      float o = __shfl_up(v, off, 64);
      if (tid >= off) v += o;
    }
    sAc[tid] = v;
    float alast = __shfl(v, 63, 64);
    sdecay[tid] = expf(alast - v);
    acs[((size_t)((b*NHEADS + h)*NCHUNK + c))*64 + tid] = v;
  }
  __syncthreads();
  for (int i = tid; i < 64*128; i += 256) {
    int s = i >> 7, n = i & 127;
    float v = us2f(bcact[(size_t)(t0 + s) * 256 + n]) * sdt[s] * sdecay[s];
    sBt[n*72 + s] = f2us(v);
  }
  for (int i = tid; i < 64*64; i += 256) {
    int s = i >> 6, p = i & 63;
    int cx = h * HEADDIM + p;
    int lb = c * CHUNK + s;
    float acc = cb[cx];
    #pragma unroll
    for (int j = 0; j < 4; ++j) {
      int ll = lb - 3 + j;
      if (ll >= 0)
        acc += cw[cx*4 + j] * us2f(proj[(size_t)(b*SEQ + ll) * NPROJ + DINNER + cx]);
    }
    float xh = acc / (1.f + expf(-acc));
    sXh[p*72 + s] = f2us(xh);
  }
  {
    const float* gr = gbuf + ((size_t)(b*NCHUNK + c)) * 4096;
    for (int i = tid; i < 4096; i += 256) {
      int l = i >> 6, s = i & 63;
      float w = (s <= l) ? gr[i] * expf(sAc[l] - sAc[s]) * sdt[s] : 0.f;
      sW[l*72 + s] = f2us(w);
    }
  }
  __syncthreads();

  floatx4 accy[4];
  #pragma unroll
  for (int j = 0; j < 4; ++j) accy[j] = (floatx4){0.f, 0.f, 0.f, 0.f};
  #pragma unroll
  for (int k0 = 0; k0 < 64; k0 += 32) {
    short8 af = *(const short8*)(sW + (wave*16 + fr)*72 + k0 + fq*8);
    #pragma unroll
    for (int j = 0; j < 4; ++j) {
      short8 bf = *(const short8*)(sXh + (j*16 + fr)*72 + k0 + fq*8);
      accy[j] = __builtin_amdgcn_mfma_f32_16x16x32_bf16(af, bf, accy[j], 0, 0, 0);
    }
  }
  const float Dh = Dv[h];
  #pragma unroll
  for (int j = 0; j < 4; ++j) {
    int p = j*16 + fr;
    #pragma unroll
    for (int r = 0; r < 4; ++r) {
      int l = wave*16 + fq*4 + r;
      float yd = accy[j][r] + us2f(sXh[p*72 + l]) * Dh;
      yscan[(size_t)(t0 + l) * DINNER + h*HEADDIM + p] = f2us(yd);
    }
  }
  floatx4 accs[8];
  #pragma unroll
  for (int j = 0; j < 8; ++j) accs[j] = (floatx4){0.f, 0.f, 0.f, 0.f};
  #pragma unroll
  for (int k0 = 0; k0 < 64; k0 += 32) {
    short8 af = *(const short8*)(sXh + (wave*16 + fr)*72 + k0 + fq*8);
    #pragma unroll
    for (int j = 0; j < 8; ++j) {
      short8 bf = *(const short8*)(sBt + (j*16 + fr)*72 + k0 + fq*8);
      accs[j] = __builtin_amdgcn_mfma_f32_16x16x32_bf16(af, bf, accs[j], 0, 0, 0);
    }
  }
  const size_t csb = ((size_t)((b*NHEADS + h)*NCHUNK + c)) * (HEADDIM*DSTATE);
  #pragma unroll
  for (int j = 0; j < 8; ++j) {
    int n = j*16 + fr;
    #pragma unroll
    for (int r = 0; r < 4; ++r) {
      int p = wave*16 + fq*4 + r;
      cs[csb + p*128 + n] = f2us(accs[j][r]);
    }
  }
}

// ---- B: inter-chunk running-state scan ----
__global__ __launch_bounds__(256) void ssd_scan_states(
    unsigned short* __restrict__ cs, const float* __restrict__ acs) {
  int idx = blockIdx.x * 256 + threadIdx.x;
  int e  = idx & 8191;
  int bh = idx >> 13;
  float S = 0.f;
  for (int c = 0; c < NCHUNK; ++c) {
    float al = acs[((size_t)bh*NCHUNK + c)*64 + 63];
    size_t o = ((size_t)bh*NCHUNK + c)*(HEADDIM*DSTATE) + e;
    S = S * expf(al) + us2f(cs[o]);
    cs[o] = f2us(S);
  }
}

// ---- C (MFMA) ----
__global__ __launch_bounds__(256, 4) void ssd_phase_c_mfma(
    const unsigned short* __restrict__ bcact, const unsigned short* __restrict__ cs,
    const float* __restrict__ acs, unsigned short* __restrict__ yscan) {
  const int h = blockIdx.x & 63;
  const int c = (blockIdx.x >> 6) & 31;
  const int b = blockIdx.x >> 11;
  const int tid = threadIdx.x;
  const int t0 = b * SEQ + c * CHUNK;
  const int lane = tid & 63, wave = tid >> 6;
  const int fr = lane & 15, fq = lane >> 4;

  __shared__ __align__(16) unsigned short sC[64*136];
  __shared__ __align__(16) unsigned short sS[64*136];
  __shared__ float seAc[64];

  const size_t csb = ((size_t)((b*NHEADS + h)*NCHUNK + c)) * (HEADDIM*DSTATE);
  for (int i = tid; i < 8192; i += 256) {
    int p = i >> 7, n = i & 127;
    sS[p*136 + n] = cs[csb + i];
  }
  for (int i = tid; i < 8192; i += 256) {
    int l = i >> 7, n = i & 127;
    sC[l*136 + n] = bcact[(size_t)(t0 + l) * 256 + 128 + n];
  }
  if (tid < 64) seAc[tid] = expf(acs[((size_t)((b*NHEADS + h)*NCHUNK + c))*64 + tid]);
  __syncthreads();

  floatx4 acc[4];
  #pragma unroll
  for (int j = 0; j < 4; ++j) acc[j] = (floatx4){0.f, 0.f, 0.f, 0.f};
  #pragma unroll
  for (int k0 = 0; k0 < 128; k0 += 32) {
    short8 af = *(const short8*)(sC + (wave*16 + fr)*136 + k0 + fq*8);
    #pragma unroll
    for (int j = 0; j < 4; ++j) {
      short8 bf = *(const short8*)(sS + (j*16 + fr)*136 + k0 + fq*8);
      acc[j] = __builtin_amdgcn_mfma_f32_16x16x32_bf16(af, bf, acc[j], 0, 0, 0);
    }
  }
  #pragma unroll
  for (int j = 0; j < 4; ++j) {
    int p = j*16 + fr;
    #pragma unroll
    for (int r = 0; r < 4; ++r) {
      int l = wave*16 + fq*4 + r;
      size_t yi = (size_t)(t0 + l) * DINNER + h*HEADDIM + p;
      yscan[yi] = f2us(us2f(yscan[yi]) + acc[j][r] * seAc[l]);
    }
  }
}

__global__ __launch_bounds__(256) void gate_rmsnorm2(
    const unsigned short* __restrict__ proj, const float* __restrict__ norm_w,
    unsigned short* __restrict__ yscan) {
  const int t = blockIdx.x;
  const int tid = threadIdx.x;
  __shared__ float ybuf[DINNER];
  __shared__ float wpart[4];
  __shared__ float sinv;
  float ss = 0.f;
  for (int i = tid; i < DINNER; i += 256) {
    float zv = us2f(proj[(size_t)t * NPROJ + i]);
    float yv = us2f(yscan[(size_t)t * DINNER + i]) * (zv / (1.f + expf(-zv)));
    ybuf[i] = yv;
    ss += yv * yv;
  }
  #pragma unroll
  for (int off = 32; off > 0; off >>= 1) ss += __shfl_down(ss, off, 64);
  if ((tid & 63) == 0) wpart[tid >> 6] = ss;
  __syncthreads();
  if (tid == 0) {
    float tot = wpart[0] + wpart[1] + wpart[2] + wpart[3];
    sinv = 1.f / sqrtf(tot / (float)DINNER + 1e-5f);
  }
  __syncthreads();
  float inv = sinv;
  for (int i = tid; i < DINNER; i += 256)
    yscan[(size_t)t * DINNER + i] = f2us(ybuf[i] * inv * norm_w[i]);
}

// ================= FALLBACK path =================
__global__ __launch_bounds__(512) void ssd_fused(
    const unsigned short* __restrict__ proj, const float* __restrict__ dtr,
    const float* __restrict__ cw, const float* __restrict__ cb,
    const float* __restrict__ A_log, const float* __restrict__ dt_bias,
    unsigned short* __restrict__ yscan) {
  const int h = blockIdx.x & 63;
  const int b = blockIdx.x >> 6;
  const int tid = threadIdx.x;

  __shared__ unsigned short sB[64*130];
  __shared__ unsigned short sC[64*130];
  __shared__ unsigned short sX[64*66];
  __shared__ float sW[64*65];
  __shared__ float sdt[64], sAc[64], sdecay[64], seAc[64];

  const float Ah = -expf(A_log[h]);
  const float dbias = dt_bias[h];

  float S[16];
  #pragma unroll
  for (int j = 0; j < 16; ++j) S[j] = 0.f;

  const int lG  = tid >> 3;
  const int oc  = tid & 7;

  for (int c = 0; c < NCHUNK; ++c) {
    const int t0 = b * SEQ + c * CHUNK;
    __syncthreads();
    if (tid < 64) {
      float raw = dtr[(size_t)(t0 + tid) * NHEADS + h] + dbias;
      sdt[tid] = (raw > 20.f) ? raw : log1pf(expf(raw));
    }
    for (int i = tid; i < 64*256; i += 512) {
      int s = i >> 8, ch = i & 255;
      int cx = 4096 + ch;
      int lb = c * CHUNK + s;
      float acc = cb[cx];
      #pragma unroll
      for (int j = 0; j < 4; ++j) {
        int ll = lb - 3 + j;
        if (ll >= 0)
          acc += cw[cx*4 + j] * us2f(proj[(size_t)(b*SEQ + ll) * NPROJ + DINNER + cx]);
      }
      float v = acc / (1.f + expf(-acc));
      if (ch < 128) sB[s*130 + ch] = f2us(v);
      else          sC[s*130 + (ch - 128)] = f2us(v);
    }
    __syncthreads();
    if (tid == 0) {
      float run = 0.f;
      for (int s = 0; s < CHUNK; ++s) { run += sdt[s] * Ah; sAc[s] = run; }
    }
    __syncthreads();
    if (tid < 64) {
      float last = sAc[63];
      sdecay[tid] = expf(last - sAc[tid]);
      seAc[tid]   = expf(sAc[tid]);
    }
    for (int i = tid; i < 64*64; i += 512) {
      int s = i >> 6, p = i & 63;
      int cx = h * HEADDIM + p;
      int lb = c * CHUNK + s;
      float acc = cb[cx];
      #pragma unroll
      for (int j = 0; j < 4; ++j) {
        int ll = lb - 3 + j;
        if (ll >= 0)
          acc += cw[cx*4 + j] * us2f(proj[(size_t)(b*SEQ + ll) * NPROJ + DINNER + cx]);
      }
      float v = acc / (1.f + expf(-acc));
      sX[s*66 + p] = f2us(v * sdt[s]);
    }
    __syncthreads();

    float g[8];
    #pragma unroll
    for (int j = 0; j < 8; ++j) g[j] = 0.f;
    {
      const uint32_t* Cu = (const uint32_t*)&sC[lG * 130];
      for (int u = 0; u < 64; ++u) {
        uint32_t cv = Cu[u];
        float c0 = plo(cv), c1 = phi(cv);
        #pragma unroll
        for (int j = 0; j < 8; ++j) {
          uint32_t bv = ((const uint32_t*)&sB[(oc*8 + j) * 130])[u];
          g[j] += c0 * plo(bv) + c1 * phi(bv);
        }
      }
    }
    {
      float acl = sAc[lG];
      #pragma unroll
      for (int j = 0; j < 8; ++j) {
        int s = oc*8 + j;
        sW[lG*65 + s] = (s <= lG) ? g[j] * expf(acl - sAc[s]) : 0.f;
      }
    }
    {
      float elast = expf(sAc[63]);
      #pragma unroll
      for (int j = 0; j < 16; ++j) S[j] *= elast;
      for (int s = 0; s < CHUNK; ++s) {
        float w = sdecay[s] * us2f(sX[s*66 + lG]);
        const uint32_t* Bu = (const uint32_t*)&sB[s*130 + oc*16];
        #pragma unroll
        for (int ju = 0; ju < 8; ++ju) {
          uint32_t bv = Bu[ju];
          S[2*ju]   += plo(bv) * w;
          S[2*ju+1] += phi(bv) * w;
        }
      }
    }
    __syncthreads();
    #pragma unroll
    for (int j = 0; j < 16; ++j) sB[lG*130 + oc*16 + j] = f2us(S[j]);
    __syncthreads();
    for (int o = tid; o < CHUNK*HEADDIM; o += 512) {
      int l = o >> 6, p = o & 63;
      float yd = 0.f;
      for (int s = 0; s <= l; ++s)
        yd += sW[l*65 + s] * us2f(sX[s*66 + p]);
      float yo = 0.f;
      const uint32_t* Cu = (const uint32_t*)&sC[l * 130];
      const uint32_t* Su = (const uint32_t*)&sB[p * 130];
      for (int u = 0; u < 64; ++u) {
        uint32_t cv = Cu[u], sv = Su[u];
        yo += plo(cv) * plo(sv) + phi(cv) * phi(sv);
      }
      float y = yd + yo * seAc[l];
      yscan[(size_t)(t0 + l) * DINNER + h * HEADDIM + p] = f2us(y);
    }
  }
}

__global__ __launch_bounds__(256) void gate_rmsnorm_dskip(
    const unsigned short* __restrict__ proj, const float* __restrict__ cw,
    const float* __restrict__ cb, const float* __restrict__ Dv,
    const float* __restrict__ norm_w, unsigned short* __restrict__ yscan) {
  const int t = blockIdx.x;
  const int tid = threadIdx.x;
  const int b = t >> 11, lb = t & 2047;
  __shared__ float ybuf[DINNER];
  __shared__ float wpart[4];
  __shared__ float sinv;
  float ss = 0.f;
  for (int i = tid; i < DINNER; i += 256) {
    float zv = us2f(proj[(size_t)t * NPROJ + i]);
    float acc = cb[i];
    #pragma unroll
    for (int j = 0; j < 4; ++j) {
      int ll = lb - 3 + j;
      if (ll >= 0)
        acc += cw[i*4 + j] * us2f(proj[(size_t)(b*SEQ + ll) * NPROJ + DINNER + i]);
    }
    float xh = acc / (1.f + expf(-acc));
    float yv = us2f(yscan[(size_t)t * DINNER + i]) + xh * Dv[i >> 6];
    yv = yv * (zv / (1.f + expf(-zv)));
    ybuf[i] = yv;
    ss += yv * yv;
  }
  #pragma unroll
  for (int off = 32; off > 0; off >>= 1) ss += __shfl_down(ss, off, 64);
  if ((tid & 63) == 0) wpart[tid >> 6] = ss;
  __syncthreads();
  if (tid == 0) {
    float tot = wpart[0] + wpart[1] + wpart[2] + wpart[3];
    sinv = 1.f / sqrtf(tot / (float)DINNER + 1e-5f);
  }
  __syncthreads();
  float inv = sinv;
  for (int i = tid; i < DINNER; i += 256)
    yscan[(size_t)t * DINNER + i] = f2us(ybuf[i] * inv * norm_w[i]);
}

// ---------------- launch ----------------
extern "C" void kernel_launch(void* const* d_in, const int* in_sizes, int n_in,
                              void* d_out, int out_size, void* d_ws, size_t ws_size,
                              hipStream_t stream) {
  const float* x          = (const float*)d_in[0];
  const float* in_proj_w  = (const float*)d_in[1];
  const float* conv_w     = (const float*)d_in[2];
  const float* conv_b     = (const float*)d_in[3];
  const float* A_log      = (const float*)d_in[4];
  const float* Dv         = (const float*)d_in[5];
  const float* dt_bias    = (const float*)d_in[6];
  const float* norm_w     = (const float*)d_in[7];
  const float* out_proj_w = (const float*)d_in[8];
  float* out = (float*)d_out;

  unsigned short* proj  = (unsigned short*)d_ws;
  float*          dtr   = (float*)(proj + (size_t)TOKENS * NPROJ);
  unsigned short* yscan = (unsigned short*)(dtr + (size_t)TOKENS * NHEADS);
  unsigned short* cs    = yscan + (size_t)TOKENS * DINNER;
  float*          acs   = (float*)(cs + (size_t)B_SZ*NHEADS*NCHUNK*HEADDIM*DSTATE);
  unsigned short* bcact = (unsigned short*)(acs + (size_t)B_SZ*NHEADS*NCHUNK*64);
  float*          gbuf  = (float*)(bcact + (size_t)TOKENS*256);
  const size_t NEEDED = (size_t)((char*)(gbuf + (size_t)B_SZ*NCHUNK*4096) - (char*)d_ws);

  unsigned short* xb  = cs;                                  // TOKENS*DMODEL
  unsigned short* wib = xb + (size_t)TOKENS * DMODEL;        // NPROJ*DMODEL
  unsigned short* wob = proj;                                // DMODEL*DINNER

  if (ws_size >= NEEDED) {
    cast_f32_bf16<<<(TOKENS*DMODEL)/1024, 256, 0, stream>>>(x, xb, TOKENS*DMODEL);
    cast_f32_bf16<<<((size_t)NPROJ*DMODEL)/1024, 256, 0, stream>>>(in_proj_w, wib, NPROJ*DMODEL);
    {
      int nwg = (TOKENS/128) * (NPROJ/256);   // 32*33 = 1056, %8 == 0
      gemm_bt_p3<1><<<nwg, 256, 0, stream>>>(xb, wib, proj, TOKENS, NPROJ, DMODEL, TOKENS/128);
    }
    dt_gemm<<<TOKENS/64, 256, 0, stream>>>(x, in_proj_w, dtr);
    bc_conv_g<<<B_SZ*NCHUNK, 256, 0, stream>>>(proj, conv_w, conv_b, bcact, gbuf);
    ssd_phase_a2_mfma<<<B_SZ*NCHUNK*NHEADS, 256, 0, stream>>>(
        proj, bcact, dtr, conv_w, conv_b, A_log, dt_bias, gbuf, Dv, cs, acs, yscan);
    ssd_scan_states<<<(B_SZ*NHEADS*HEADDIM*DSTATE)/256, 256, 0, stream>>>(cs, acs);
    ssd_phase_c_mfma<<<B_SZ*NCHUNK*NHEADS, 256, 0, stream>>>(bcact, cs, acs, yscan);
    gate_rmsnorm2<<<TOKENS, 256, 0, stream>>>(proj, norm_w, yscan);
    cast_f32_bf16<<<((size_t)DMODEL*DINNER)/1024, 256, 0, stream>>>(out_proj_w, wob, DMODEL*DINNER);
    {
      int nwg = (TOKENS/128) * (DMODEL/256);  // 32*8 = 256, %8 == 0
      gemm_bt_p3<0><<<nwg, 256, 0, stream>>>(yscan, wob, out, TOKENS, DMODEL, DINNER, TOKENS/128);
    }
  } else {
    {
      dim3 grid(NPROJ/128, TOKENS/128);
      gemm_nt<float, unsigned short><<<grid, 256, 0, stream>>>(
          x, in_proj_w, proj, TOKENS, NPROJ, DMODEL);
    }
    dt_gemm<<<TOKENS/64, 256, 0, stream>>>(x, in_proj_w, dtr);
    ssd_fused<<<B_SZ*NHEADS, 512, 0, stream>>>(proj, dtr, conv_w, conv_b,
                                               A_log, dt_bias, yscan);
    gate_rmsnorm_dskip<<<TOKENS, 256, 0, stream>>>(proj, conv_w, conv_b, Dv, norm_w, yscan);
    {
      dim3 grid(DMODEL/128, TOKENS/128);
      gemm_nt<unsigned short, float><<<grid, 256, 0, stream>>>(
          yscan, out_proj_w, out, TOKENS, DMODEL, DINNER);
    }
  }
}

// Round 5
// 702.806 us; speedup vs baseline: 1.1486x; 1.1486x over previous
//
#include <hip/hip_runtime.h>
#include <cstddef>
#include <cstdint>

// ---------------- problem constants ----------------
#define B_SZ    2
#define SEQ     2048
#define DMODEL  2048
#define DINNER  4096
#define DSTATE  128
#define NHEADS  64
#define HEADDIM 64
#define DXBC    4352          // DINNER + 2*DSTATE
#define NPROJ   8448          // DINNER + DXBC (z | xBC); dt handled separately in fp32
#define CHUNK   64
#define NCHUNK  32
#define TOKENS  (B_SZ*SEQ)    // 4096

typedef __attribute__((ext_vector_type(8))) short short8;   // 8 x bf16
typedef __attribute__((ext_vector_type(4))) float floatx4;

// ---- bf16 <-> f32 helpers ----
__device__ inline float us2f(unsigned short u) {
  union { uint32_t i; float f; } c; c.i = ((uint32_t)u) << 16; return c.f;
}
__device__ inline unsigned short f2us(float f) {
  union { float f; uint32_t i; } c; c.f = f;
  uint32_t r = (c.i + 0x7fffu + ((c.i >> 16) & 1u)) >> 16;
  return (unsigned short)r;
}
__device__ inline float plo(uint32_t v) {
  union { uint32_t i; float f; } c; c.i = v << 16; return c.f;
}
__device__ inline float phi(uint32_t v) {
  union { uint32_t i; float f; } c; c.i = v & 0xffff0000u; return c.f;
}

// ---------------- f32 -> bf16 cast (vectorized) ----------------
__global__ __launch_bounds__(256) void cast_f32_bf16(
    const float* __restrict__ src, unsigned short* __restrict__ dst, int n) {
  int i = (blockIdx.x * 256 + threadIdx.x) * 4;
  if (i < n) {
    float4 v = *(const float4*)(src + i);
    ushort4 o;
    o.x = f2us(v.x); o.y = f2us(v.y); o.z = f2us(v.z); o.w = f2us(v.w);
    *(ushort4*)(dst + i) = o;
  }
}

// ======= pipelined MFMA bf16 NT GEMM: C[M,N] = A[M,K] @ B[N,K]^T ============
// BMT x 256 tile, 256 threads (4 waves, 1M x 4N), per-wave out BMT x 64.
// K advanced in 32-wide halves. LDS = ring of 3 half-buffers -> 2 blocks/CU.
// Depth-2 prefetch, counted vmcnt (= loads/iter, never 0 mid-loop).
// R3-proven single-phase loop (R4 two-phase split was neutral; reverted).
// Bank swizzle for 64B rows: 16B-slot ^= (row>>1)&3, applied both-sides.
// XCD-aware bijective blockIdx remap (nwg % 8 == 0 for both call sites).
// BMT=128 for in-proj (1056 wgs); BMT=64 for out-proj (512 wgs -> 2 blk/CU,
// fixes its 256-wg 1-blk/CU occupancy hole).
template<int OUT_BF16, int BMT>
__global__ __launch_bounds__(256, 2) void gemm_bt_p3(
    const unsigned short* __restrict__ A, const unsigned short* __restrict__ B,
    void* __restrict__ Cout, int M, int N, int K, int GM) {
  constexpr int ACH   = BMT / 64;           // A chunks per half-K (1 or 2)
  constexpr int NCH   = ACH + 4;            // loads per iter per thread
  constexpr int ABASE = ACH * 2048;         // shorts: A region size
  constexpr int BUFS  = (BMT + 256) * 32;   // shorts per ring slot
  constexpr int NI    = BMT / 16;           // A fragment tiles
  __shared__ __align__(16) unsigned short sT[3 * BUFS];
  const int tid  = threadIdx.x;
  const int lane = tid & 63;
  const int wc   = tid >> 6;        // wave 0..3 = N quadrant
  const int fr   = lane & 15;
  const int fq   = lane >> 4;

  const int nwg  = gridDim.x;
  int wgid = blockIdx.x;
  if ((nwg & 7) == 0) wgid = (wgid & 7) * (nwg >> 3) + (wgid >> 3);
  const int bm = (wgid % GM) * BMT;
  const int bn = (wgid / GM) * 256;

  floatx4 acc[NI][4];
  #pragma unroll
  for (int i = 0; i < NI; ++i)
    #pragma unroll
    for (int j = 0; j < 4; ++j) acc[i][j] = (floatx4){0.f, 0.f, 0.f, 0.f};

  auto stage = [&](int rb, int kb) {
    unsigned short* dst = (unsigned short*)sT + rb * BUFS;
    #pragma unroll
    for (int q = 0; q < NCH; ++q) {
      if (q < ACH) {
        int i = q * 256 + tid;
        int row = i >> 2, slot = i & 3;
        const unsigned short* g =
            A + (size_t)(bm + row) * K + kb + 8 * (slot ^ ((row >> 1) & 3));
        __builtin_amdgcn_global_load_lds(
            (const __attribute__((address_space(1))) uint32_t*)g,
            (__attribute__((address_space(3))) uint32_t*)(dst + i * 8), 16, 0, 0);
      } else {
        int i = (q - ACH) * 256 + tid;
        int row = i >> 2, slot = i & 3;
        const unsigned short* g =
            B + (size_t)(bn + row) * K + kb + 8 * (slot ^ ((row >> 1) & 3));
        __builtin_amdgcn_global_load_lds(
            (const __attribute__((address_space(1))) uint32_t*)g,
            (__attribute__((address_space(3))) uint32_t*)(dst + ABASE + i * 8), 16, 0, 0);
      }
    }
  };

  const int NH = K >> 5;
  stage(0, 0);
  stage(1, 32);
  if constexpr (NCH == 6) asm volatile("s_waitcnt vmcnt(6)" ::: "memory");
  else                    asm volatile("s_waitcnt vmcnt(5)" ::: "memory");
  asm volatile("s_barrier" ::: "memory");

  int cb = 0, sb = 2;   // current ring idx, stage ring idx (h+2)
  for (int h = 0; h < NH; ++h) {
    const unsigned short* buf = (const unsigned short*)sT + cb * BUFS;
    if (h + 2 < NH) stage(sb, (h + 2) << 5);

    short8 af[NI], bf[4];
    #pragma unroll
    for (int i = 0; i < NI; ++i) {
      int row = i * 16 + fr;
      af[i] = *(const short8*)(buf + row * 32 + 8 * (fq ^ ((row >> 1) & 3)));
    }
    #pragma unroll
    for (int j = 0; j < 4; ++j) {
      int row = wc * 64 + j * 16 + fr;
      bf[j] = *(const short8*)(buf + ABASE + row * 32 + 8 * (fq ^ ((row >> 1) & 3)));
    }
    __builtin_amdgcn_s_setprio(1);
    #pragma unroll
    for (int i = 0; i < NI; ++i)
      #pragma unroll
      for (int j = 0; j < 4; ++j)
        acc[i][j] = __builtin_amdgcn_mfma_f32_16x16x32_bf16(af[i], bf[j], acc[i][j], 0, 0, 0);
    __builtin_amdgcn_s_setprio(0);

    if (h < NH - 2) {
      if constexpr (NCH == 6) asm volatile("s_waitcnt vmcnt(6) lgkmcnt(0)" ::: "memory");
      else                    asm volatile("s_waitcnt vmcnt(5) lgkmcnt(0)" ::: "memory");
    } else {
      asm volatile("s_waitcnt vmcnt(0) lgkmcnt(0)" ::: "memory");
    }
    asm volatile("s_barrier" ::: "memory");
    cb = (cb == 2) ? 0 : cb + 1;
    sb = (sb == 2) ? 0 : sb + 1;
  }

  // epilogue
  #pragma unroll
  for (int i = 0; i < NI; ++i) {
    #pragma unroll
    for (int j = 0; j < 4; ++j) {
      int col = bn + wc * 64 + j * 16 + fr;
      #pragma unroll
      for (int r = 0; r < 4; ++r) {
        int row = bm + i * 16 + fq * 4 + r;
        if (OUT_BF16)
          ((unsigned short*)Cout)[(size_t)row * N + col] = f2us(acc[i][j][r]);
        else
          ((float*)Cout)[(size_t)row * N + col] = acc[i][j][r];
      }
    }
  }
}

// ---------------- fp32 tiled NT GEMM (fallback path only) ----------------
__device__ inline void loadA4(const float* p, float* d) {
  float4 v = *(const float4*)p; d[0]=v.x; d[1]=v.y; d[2]=v.z; d[3]=v.w;
}
__device__ inline void loadA4(const unsigned short* p, float* d) {
  ushort4 v = *(const ushort4*)p;
  d[0]=us2f(v.x); d[1]=us2f(v.y); d[2]=us2f(v.z); d[3]=us2f(v.w);
}
__device__ inline void store8(float* C, size_t off, const float* v) {
  *(float4*)(C + off)     = make_float4(v[0], v[1], v[2], v[3]);
  *(float4*)(C + off + 4) = make_float4(v[4], v[5], v[6], v[7]);
}
__device__ inline void store8(unsigned short* C, size_t off, const float* v) {
  ushort4 a; a.x=f2us(v[0]); a.y=f2us(v[1]); a.z=f2us(v[2]); a.w=f2us(v[3]);
  ushort4 b; b.x=f2us(v[4]); b.y=f2us(v[5]); b.z=f2us(v[6]); b.w=f2us(v[7]);
  *(ushort4*)(C + off) = a; *(ushort4*)(C + off + 4) = b;
}

template<typename AT, typename OT>
__global__ __launch_bounds__(256) void gemm_nt(
    const AT* __restrict__ A, const float* __restrict__ Bw,
    OT* __restrict__ C, int M, int N, int K) {
  __shared__ float As[16][128+4];
  __shared__ float Bs[16][128+4];
  const int bm = blockIdx.y * 128;
  const int bn = blockIdx.x * 128;
  const int tid = threadIdx.x;
  const int tx = tid & 15, ty = tid >> 4;

  float acc[8][8];
  #pragma unroll
  for (int i = 0; i < 8; ++i)
    #pragma unroll
    for (int j = 0; j < 8; ++j) acc[i][j] = 0.f;

  for (int k0 = 0; k0 < K; k0 += 16) {
    #pragma unroll
    for (int r = 0; r < 2; ++r) {
      int i = tid + r * 256;
      int m  = i >> 2;
      int kv = (i & 3) << 2;
      float va[4];
      loadA4(A + (size_t)(bm + m) * K + k0 + kv, va);
      As[kv+0][m] = va[0]; As[kv+1][m] = va[1]; As[kv+2][m] = va[2]; As[kv+3][m] = va[3];
      float vb[4] = {0.f, 0.f, 0.f, 0.f};
      if (bn + m < N) loadA4(Bw + (size_t)(bn + m) * K + k0 + kv, vb);
      Bs[kv+0][m] = vb[0]; Bs[kv+1][m] = vb[1]; Bs[kv+2][m] = vb[2]; Bs[kv+3][m] = vb[3];
    }
    __syncthreads();
    #pragma unroll
    for (int kk = 0; kk < 16; ++kk) {
      float ra[8], rb[8];
      *(float4*)&ra[0] = *(const float4*)&As[kk][ty*8];
      *(float4*)&ra[4] = *(const float4*)&As[kk][ty*8+4];
      *(float4*)&rb[0] = *(const float4*)&Bs[kk][tx*8];
      *(float4*)&rb[4] = *(const float4*)&Bs[kk][tx*8+4];
      #pragma unroll
      for (int i = 0; i < 8; ++i)
        #pragma unroll
        for (int j = 0; j < 8; ++j) acc[i][j] += ra[i] * rb[j];
    }
    __syncthreads();
  }
  #pragma unroll
  for (int i = 0; i < 8; ++i) {
    int m  = bm + ty*8 + i;
    int n0 = bn + tx*8;
    if (n0 < N) store8(C, (size_t)m * N + n0, &acc[i][0]);
  }
}

// ---------------- dt GEMM (fp32, tiled) ----------------
__global__ __launch_bounds__(256) void dt_gemm(
    const float* __restrict__ x, const float* __restrict__ W,
    float* __restrict__ dtr) {
  __shared__ float sX[32][64];   // [kk][token]
  __shared__ float sW[32][64];   // [kk][head]
  const int tid = threadIdx.x;
  const int t0 = blockIdx.x * 64;
  const int tx = tid & 15;
  const int ty = tid >> 4;
  const float* Wdt = W + (size_t)NPROJ * DMODEL;

  float acc[4][4];
  #pragma unroll
  for (int i = 0; i < 4; ++i)
    #pragma unroll
    for (int j = 0; j < 4; ++j) acc[i][j] = 0.f;

  const int r  = tid >> 3;
  const int kq = (tid & 7) * 4;

  for (int k0 = 0; k0 < DMODEL; k0 += 32) {
    __syncthreads();
    #pragma unroll
    for (int rr = 0; rr < 2; ++rr) {
      int t = r + rr * 32;
      float4 v = *(const float4*)(x + (size_t)(t0 + t) * DMODEL + k0 + kq);
      sX[kq+0][t] = v.x; sX[kq+1][t] = v.y; sX[kq+2][t] = v.z; sX[kq+3][t] = v.w;
    }
    #pragma unroll
    for (int rr = 0; rr < 2; ++rr) {
      int hh = r + rr * 32;
      float4 v = *(const float4*)(Wdt + (size_t)hh * DMODEL + k0 + kq);
      sW[kq+0][hh] = v.x; sW[kq+1][hh] = v.y; sW[kq+2][hh] = v.z; sW[kq+3][hh] = v.w;
    }
    __syncthreads();
    #pragma unroll
    for (int kk = 0; kk < 32; ++kk) {
      float4 ra = *(const float4*)&sX[kk][ty*4];
      float4 rb = *(const float4*)&sW[kk][tx*4];
      float a[4] = {ra.x, ra.y, ra.z, ra.w};
      float b[4] = {rb.x, rb.y, rb.z, rb.w};
      #pragma unroll
      for (int i = 0; i < 4; ++i)
        #pragma unroll
        for (int j = 0; j < 4; ++j)
          acc[i][j] += a[i] * b[j];
    }
  }
  #pragma unroll
  for (int i = 0; i < 4; ++i) {
    float4 o = make_float4(acc[i][0], acc[i][1], acc[i][2], acc[i][3]);
    *(float4*)(dtr + (size_t)(t0 + ty*4 + i) * NHEADS + tx*4) = o;
  }
}

// ================= split-scan path =================
// R5: conv input staged ONCE in LDS (67 halo rows), all global bf16 traffic
// vectorized to short8 (was scalar 2B loads x4 taps).
__global__ __launch_bounds__(256) void bc_conv_g(
    const unsigned short* __restrict__ proj, const float* __restrict__ cw,
    const float* __restrict__ cb, unsigned short* __restrict__ bcact,
    float* __restrict__ gbuf) {
  const int c = blockIdx.x & 31;
  const int b = blockIdx.x >> 5;
  const int tid = threadIdx.x;
  const int t0 = b * SEQ + c * CHUNK;
  __shared__ __align__(16) unsigned short sIn[67 * 256];
  __shared__ __align__(16) unsigned short sB[64 * 136];
  __shared__ __align__(16) unsigned short sC[64 * 136];
  __shared__ float scw[256 * 4];
  __shared__ float scb[256];

  *(float4*)&scw[tid * 4] = *(const float4*)(cw + (size_t)(4096 + tid) * 4);
  scb[tid] = cb[4096 + tid];

  for (int i = tid; i < 67 * 32; i += 256) {
    int r = i >> 5, ch0 = (i & 31) * 8;
    int ll = c * CHUNK - 3 + r;
    short8 v = {0,0,0,0,0,0,0,0};
    if (ll >= 0)
      v = *(const short8*)(proj + (size_t)(b * SEQ + ll) * NPROJ + 8192 + ch0);
    *(short8*)&sIn[r * 256 + ch0] = v;
  }
  __syncthreads();

  for (int i = tid; i < 64 * 32; i += 256) {
    int s = i >> 5, ch0 = (i & 31) * 8;
    short8 i0 = *(const short8*)&sIn[(s + 0) * 256 + ch0];
    short8 i1 = *(const short8*)&sIn[(s + 1) * 256 + ch0];
    short8 i2 = *(const short8*)&sIn[(s + 2) * 256 + ch0];
    short8 i3 = *(const short8*)&sIn[(s + 3) * 256 + ch0];
    short8 o;
    #pragma unroll
    for (int e = 0; e < 8; ++e) {
      int ch = ch0 + e;
      float a = scb[ch]
        + scw[ch*4+0] * us2f((unsigned short)i0[e])
        + scw[ch*4+1] * us2f((unsigned short)i1[e])
        + scw[ch*4+2] * us2f((unsigned short)i2[e])
        + scw[ch*4+3] * us2f((unsigned short)i3[e]);
      float v = a / (1.f + expf(-a));
      o[e] = (short)f2us(v);
    }
    if (ch0 < 128) *(short8*)&sB[s * 136 + ch0] = o;
    else           *(short8*)&sC[s * 136 + (ch0 - 128)] = o;
    *(short8*)(bcact + (size_t)(t0 + s) * 256 + ch0) = o;
  }
  __syncthreads();

  const int l = tid >> 2, q = tid & 3;
  float g[16];
  #pragma unroll
  for (int j = 0; j < 16; ++j) g[j] = 0.f;
  const uint32_t* Cu = (const uint32_t*)&sC[l * 136];
  for (int u = 0; u < 64; ++u) {
    uint32_t cv = Cu[u];
    float c0 = plo(cv), c1 = phi(cv);
    #pragma unroll
    for (int j = 0; j < 16; ++j) {
      uint32_t bv = ((const uint32_t*)&sB[(q*16 + j) * 136])[u];
      g[j] += c0 * plo(bv) + c1 * phi(bv);
    }
  }
  float* gr = gbuf + ((size_t)(b*NCHUNK + c)) * 4096 + l*64 + q*16;
  #pragma unroll
  for (int j = 0; j < 4; ++j)
    *(float4*)(gr + j*4) = make_float4(g[j*4], g[j*4+1], g[j*4+2], g[j*4+3]);
}

// ---- A2 (MFMA): conv staged once in LDS; vectorized staging ----
__global__ __launch_bounds__(256, 3) void ssd_phase_a2_mfma(
    const unsigned short* __restrict__ proj, const unsigned short* __restrict__ bcact,
    const float* __restrict__ dtr, const float* __restrict__ cw,
    const float* __restrict__ cb, const float* __restrict__ A_log,
    const float* __restrict__ dt_bias, const float* __restrict__ gbuf,
    const float* __restrict__ Dv,
    unsigned short* __restrict__ cs, float* __restrict__ acs,
    unsigned short* __restrict__ yscan) {
  const int h = blockIdx.x & 63;
  const int c = (blockIdx.x >> 6) & 31;
  const int b = blockIdx.x >> 11;
  const int tid = threadIdx.x;
  const int t0 = b * SEQ + c * CHUNK;
  const int lane = tid & 63, wave = tid >> 6;
  const int fr = lane & 15, fq = lane >> 4;

  __shared__ __align__(16) unsigned short sIn[67 * 64];
  __shared__ __align__(16) unsigned short sBt[128*72];
  __shared__ __align__(16) unsigned short sXh[64*72];
  __shared__ __align__(16) unsigned short sW[64*72];
  __shared__ float cwl[64 * 4];
  __shared__ float cbl[64];
  __shared__ float sdt[64], sAc[64], sdecay[64];

  const float Ah = -expf(A_log[h]);
  if (tid < 64) {
    float raw = dtr[(size_t)(t0 + tid) * NHEADS + h] + dt_bias[h];
    float dt = (raw > 20.f) ? raw : log1pf(expf(raw));
    sdt[tid] = dt;
    float v = dt * Ah;
    #pragma unroll
    for (int off = 1; off < 64; off <<= 1) {
      float o = __shfl_up(v, off, 64);
      if (tid >= off) v += o;
    }
    sAc[tid] = v;
    float alast = __shfl(v, 63, 64);
    sdecay[tid] = expf(alast - v);
    acs[((size_t)((b*NHEADS + h)*NCHUNK + c))*64 + tid] = v;
  }
  if (tid >= 64 && tid < 128) {
    int p = tid - 64;
    *(float4*)&cwl[p * 4] = *(const float4*)(cw + (size_t)(h * HEADDIM + p) * 4);
    cbl[p] = cb[h * HEADDIM + p];
  }
  for (int i = tid; i < 67 * 8; i += 256) {
    int r = i >> 3, p0 = (i & 7) * 8;
    int ll = c * CHUNK - 3 + r;
    short8 v = {0,0,0,0,0,0,0,0};
    if (ll >= 0)
      v = *(const short8*)(proj + (size_t)(b * SEQ + ll) * NPROJ + DINNER + h * HEADDIM + p0);
    *(short8*)&sIn[r * 64 + p0] = v;
  }
  __syncthreads();

  // Bt'[n][s] = B[s][n]*dt[s]*decay[s]  (vector read, transposed scalar write)
  for (int i = tid; i < 64 * 16; i += 256) {
    int s = i >> 4, n0 = (i & 15) * 8;
    float sc = sdt[s] * sdecay[s];
    short8 v = *(const short8*)(bcact + (size_t)(t0 + s) * 256 + n0);
    #pragma unroll
    for (int e = 0; e < 8; ++e)
      sBt[(n0 + e) * 72 + s] = f2us(us2f((unsigned short)v[e]) * sc);
  }
  // Xh[p][s] = silu(conv(sIn))  (LDS-vector read, transposed scalar write)
  for (int i = tid; i < 64 * 8; i += 256) {
    int s = i >> 3, p0 = (i & 7) * 8;
    short8 i0 = *(const short8*)&sIn[(s + 0) * 64 + p0];
    short8 i1 = *(const short8*)&sIn[(s + 1) * 64 + p0];
    short8 i2 = *(const short8*)&sIn[(s + 2) * 64 + p0];
    short8 i3 = *(const short8*)&sIn[(s + 3) * 64 + p0];
    #pragma unroll
    for (int e = 0; e < 8; ++e) {
      int p = p0 + e;
      float a = cbl[p]
        + cwl[p*4+0] * us2f((unsigned short)i0[e])
        + cwl[p*4+1] * us2f((unsigned short)i1[e])
        + cwl[p*4+2] * us2f((unsigned short)i2[e])
        + cwl[p*4+3] * us2f((unsigned short)i3[e]);
      float xh = a / (1.f + expf(-a));
      sXh[p * 72 + s] = f2us(xh);
    }
  }
  // W'[l][s]
  {
    const float* gr = gbuf + ((size_t)(b*NCHUNK + c)) * 4096;
    for (int i = tid; i < 512; i += 256) {
      int l = i >> 3, s0 = (i & 7) * 8;
      float4 g0 = *(const float4*)(gr + l * 64 + s0);
      float4 g1 = *(const float4*)(gr + l * 64 + s0 + 4);
      float gv[8] = {g0.x, g0.y, g0.z, g0.w, g1.x, g1.y, g1.z, g1.w};
      float acl = sAc[l];
      short8 o;
      #pragma unroll
      for (int e = 0; e < 8; ++e) {
        int s = s0 + e;
        float w = (s <= l) ? gv[e] * expf(acl - sAc[s]) * sdt[s] : 0.f;
        o[e] = (short)f2us(w);
      }
      *(short8*)&sW[l * 72 + s0] = o;
    }
  }
  __syncthreads();

  floatx4 accy[4];
  #pragma unroll
  for (int j = 0; j < 4; ++j) accy[j] = (floatx4){0.f, 0.f, 0.f, 0.f};
  #pragma unroll
  for (int k0 = 0; k0 < 64; k0 += 32) {
    short8 af = *(const short8*)(sW + (wave*16 + fr)*72 + k0 + fq*8);
    #pragma unroll
    for (int j = 0; j < 4; ++j) {
      short8 bf = *(const short8*)(sXh + (j*16 + fr)*72 + k0 + fq*8);
      accy[j] = __builtin_amdgcn_mfma_f32_16x16x32_bf16(af, bf, accy[j], 0, 0, 0);
    }
  }
  const float Dh = Dv[h];
  #pragma unroll
  for (int j = 0; j < 4; ++j) {
    int p = j*16 + fr;
    #pragma unroll
    for (int r = 0; r < 4; ++r) {
      int l = wave*16 + fq*4 + r;
      float yd = accy[j][r] + us2f(sXh[p*72 + l]) * Dh;
      yscan[(size_t)(t0 + l) * DINNER + h*HEADDIM + p] = f2us(yd);
    }
  }
  floatx4 accs[8];
  #pragma unroll
  for (int j = 0; j < 8; ++j) accs[j] = (floatx4){0.f, 0.f, 0.f, 0.f};
  #pragma unroll
  for (int k0 = 0; k0 < 64; k0 += 32) {
    short8 af = *(const short8*)(sXh + (wave*16 + fr)*72 + k0 + fq*8);
    #pragma unroll
    for (int j = 0; j < 8; ++j) {
      short8 bf = *(const short8*)(sBt + (j*16 + fr)*72 + k0 + fq*8);
      accs[j] = __builtin_amdgcn_mfma_f32_16x16x32_bf16(af, bf, accs[j], 0, 0, 0);
    }
  }
  const size_t csb = ((size_t)((b*NHEADS + h)*NCHUNK + c)) * (HEADDIM*DSTATE);
  #pragma unroll
  for (int j = 0; j < 8; ++j) {
    int n = j*16 + fr;
    #pragma unroll
    for (int r = 0; r < 4; ++r) {
      int p = wave*16 + fq*4 + r;
      cs[csb + p*128 + n] = f2us(accs[j][r]);
    }
  }
}

// ---- B: inter-chunk running-state scan (vectorized, 8 elems/thread) ----
__global__ __launch_bounds__(256) void ssd_scan_states(
    unsigned short* __restrict__ cs, const float* __restrict__ acs) {
  int idx = blockIdx.x * 256 + threadIdx.x;   // grid 512 -> 131072 threads
  int bh = idx >> 10;
  int e0 = (idx & 1023) * 8;
  float S[8];
  #pragma unroll
  for (int j = 0; j < 8; ++j) S[j] = 0.f;
  for (int c = 0; c < NCHUNK; ++c) {
    float al = expf(acs[((size_t)bh*NCHUNK + c)*64 + 63]);
    size_t o = ((size_t)bh*NCHUNK + c)*(HEADDIM*DSTATE) + e0;
    short8 v = *(const short8*)(cs + o);
    short8 w;
    #pragma unroll
    for (int j = 0; j < 8; ++j) {
      S[j] = S[j] * al + us2f((unsigned short)v[j]);
      w[j] = (short)f2us(S[j]);
    }
    *(short8*)(cs + o) = w;
  }
}

// ---- C (MFMA): vectorized staging ----
__global__ __launch_bounds__(256, 4) void ssd_phase_c_mfma(
    const unsigned short* __restrict__ bcact, const unsigned short* __restrict__ cs,
    const float* __restrict__ acs, unsigned short* __restrict__ yscan) {
  const int h = blockIdx.x & 63;
  const int c = (blockIdx.x >> 6) & 31;
  const int b = blockIdx.x >> 11;
  const int tid = threadIdx.x;
  const int t0 = b * SEQ + c * CHUNK;
  const int lane = tid & 63, wave = tid >> 6;
  const int fr = lane & 15, fq = lane >> 4;

  __shared__ __align__(16) unsigned short sC[64*136];
  __shared__ __align__(16) unsigned short sS[64*136];
  __shared__ float seAc[64];

  const size_t csb = ((size_t)((b*NHEADS + h)*NCHUNK + c)) * (HEADDIM*DSTATE);
  for (int i = tid; i < 1024; i += 256) {
    int p = i >> 4, n0 = (i & 15) * 8;
    *(short8*)&sS[p * 136 + n0] = *(const short8*)(cs + csb + p * 128 + n0);
  }
  for (int i = tid; i < 1024; i += 256) {
    int l = i >> 4, n0 = (i & 15) * 8;
    *(short8*)&sC[l * 136 + n0] =
        *(const short8*)(bcact + (size_t)(t0 + l) * 256 + 128 + n0);
  }
  if (tid < 64) seAc[tid] = expf(acs[((size_t)((b*NHEADS + h)*NCHUNK + c))*64 + tid]);
  __syncthreads();

  floatx4 acc[4];
  #pragma unroll
  for (int j = 0; j < 4; ++j) acc[j] = (floatx4){0.f, 0.f, 0.f, 0.f};
  #pragma unroll
  for (int k0 = 0; k0 < 128; k0 += 32) {
    short8 af = *(const short8*)(sC + (wave*16 + fr)*136 + k0 + fq*8);
    #pragma unroll
    for (int j = 0; j < 4; ++j) {
      short8 bf = *(const short8*)(sS + (j*16 + fr)*136 + k0 + fq*8);
      acc[j] = __builtin_amdgcn_mfma_f32_16x16x32_bf16(af, bf, acc[j], 0, 0, 0);
    }
  }
  #pragma unroll
  for (int j = 0; j < 4; ++j) {
    int p = j*16 + fr;
    #pragma unroll
    for (int r = 0; r < 4; ++r) {
      int l = wave*16 + fq*4 + r;
      size_t yi = (size_t)(t0 + l) * DINNER + h*HEADDIM + p;
      yscan[yi] = f2us(us2f(yscan[yi]) + acc[j][r] * seAc[l]);
    }
  }
}

// ---- gate+rmsnorm: registers instead of LDS ybuf, short8 I/O ----
__global__ __launch_bounds__(256) void gate_rmsnorm2(
    const unsigned short* __restrict__ proj, const float* __restrict__ norm_w,
    unsigned short* __restrict__ yscan) {
  const int t = blockIdx.x;
  const int tid = threadIdx.x;
  __shared__ float wpart[4];
  __shared__ float sinv;
  float yv[16];
  float ss = 0.f;
  #pragma unroll
  for (int g = 0; g < 2; ++g) {
    int i = (g * 256 + tid) * 8;
    short8 z8 = *(const short8*)(proj + (size_t)t * NPROJ + i);
    short8 y8 = *(const short8*)(yscan + (size_t)t * DINNER + i);
    #pragma unroll
    for (int e = 0; e < 8; ++e) {
      float zv = us2f((unsigned short)z8[e]);
      float v = us2f((unsigned short)y8[e]) * (zv / (1.f + expf(-zv)));
      yv[g*8+e] = v;
      ss += v * v;
    }
  }
  #pragma unroll
  for (int off = 32; off > 0; off >>= 1) ss += __shfl_down(ss, off, 64);
  if ((tid & 63) == 0) wpart[tid >> 6] = ss;
  __syncthreads();
  if (tid == 0) {
    float tot = wpart[0] + wpart[1] + wpart[2] + wpart[3];
    sinv = 1.f / sqrtf(tot / (float)DINNER + 1e-5f);
  }
  __syncthreads();
  float inv = sinv;
  #pragma unroll
  for (int g = 0; g < 2; ++g) {
    int i = (g * 256 + tid) * 8;
    float4 w0 = *(const float4*)(norm_w + i);
    float4 w1 = *(const float4*)(norm_w + i + 4);
    float wv[8] = {w0.x, w0.y, w0.z, w0.w, w1.x, w1.y, w1.z, w1.w};
    short8 o;
    #pragma unroll
    for (int e = 0; e < 8; ++e)
      o[e] = (short)f2us(yv[g*8+e] * inv * wv[e]);
    *(short8*)(yscan + (size_t)t * DINNER + i) = o;
  }
}

// ================= FALLBACK path =================
__global__ __launch_bounds__(512) void ssd_fused(
    const unsigned short* __restrict__ proj, const float* __restrict__ dtr,
    const float* __restrict__ cw, const float* __restrict__ cb,
    const float* __restrict__ A_log, const float* __restrict__ dt_bias,
    unsigned short* __restrict__ yscan) {
  const int h = blockIdx.x & 63;
  const int b = blockIdx.x >> 6;
  const int tid = threadIdx.x;

  __shared__ unsigned short sB[64*130];
  __shared__ unsigned short sC[64*130];
  __shared__ unsigned short sX[64*66];
  __shared__ float sW[64*65];
  __shared__ float sdt[64], sAc[64], sdecay[64], seAc[64];

  const float Ah = -expf(A_log[h]);
  const float dbias = dt_bias[h];

  float S[16];
  #pragma unroll
  for (int j = 0; j < 16; ++j) S[j] = 0.f;

  const int lG  = tid >> 3;
  const int oc  = tid & 7;

  for (int c = 0; c < NCHUNK; ++c) {
    const int t0 = b * SEQ + c * CHUNK;
    __syncthreads();
    if (tid < 64) {
      float raw = dtr[(size_t)(t0 + tid) * NHEADS + h] + dbias;
      sdt[tid] = (raw > 20.f) ? raw : log1pf(expf(raw));
    }
    for (int i = tid; i < 64*256; i += 512) {
      int s = i >> 8, ch = i & 255;
      int cx = 4096 + ch;
      int lb = c * CHUNK + s;
      float acc = cb[cx];
      #pragma unroll
      for (int j = 0; j < 4; ++j) {
        int ll = lb - 3 + j;
        if (ll >= 0)
          acc += cw[cx*4 + j] * us2f(proj[(size_t)(b*SEQ + ll) * NPROJ + DINNER + cx]);
      }
      float v = acc / (1.f + expf(-acc));
      if (ch < 128) sB[s*130 + ch] = f2us(v);
      else          sC[s*130 + (ch - 128)] = f2us(v);
    }
    __syncthreads();
    if (tid == 0) {
      float run = 0.f;
      for (int s = 0; s < CHUNK; ++s) { run += sdt[s] * Ah; sAc[s] = run; }
    }
    __syncthreads();
    if (tid < 64) {
      float last = sAc[63];
      sdecay[tid] = expf(last - sAc[tid]);
      seAc[tid]   = expf(sAc[tid]);
    }
    for (int i = tid; i < 64*64; i += 512) {
      int s = i >> 6, p = i & 63;
      int cx = h * HEADDIM + p;
      int lb = c * CHUNK + s;
      float acc = cb[cx];
      #pragma unroll
      for (int j = 0; j < 4; ++j) {
        int ll = lb - 3 + j;
        if (ll >= 0)
          acc += cw[cx*4 + j] * us2f(proj[(size_t)(b*SEQ + ll) * NPROJ + DINNER + cx]);
      }
      float v = acc / (1.f + expf(-acc));
      sX[s*66 + p] = f2us(v * sdt[s]);
    }
    __syncthreads();

    float g[8];
    #pragma unroll
    for (int j = 0; j < 8; ++j) g[j] = 0.f;
    {
      const uint32_t* Cu = (const uint32_t*)&sC[lG * 130];
      for (int u = 0; u < 64; ++u) {
        uint32_t cv = Cu[u];
        float c0 = plo(cv), c1 = phi(cv);
        #pragma unroll
        for (int j = 0; j < 8; ++j) {
          uint32_t bv = ((const uint32_t*)&sB[(oc*8 + j) * 130])[u];
          g[j] += c0 * plo(bv) + c1 * phi(bv);
        }
      }
    }
    {
      float acl = sAc[lG];
      #pragma unroll
      for (int j = 0; j < 8; ++j) {
        int s = oc*8 + j;
        sW[lG*65 + s] = (s <= lG) ? g[j] * expf(acl - sAc[s]) : 0.f;
      }
    }
    {
      float elast = expf(sAc[63]);
      #pragma unroll
      for (int j = 0; j < 16; ++j) S[j] *= elast;
      for (int s = 0; s < CHUNK; ++s) {
        float w = sdecay[s] * us2f(sX[s*66 + lG]);
        const uint32_t* Bu = (const uint32_t*)&sB[s*130 + oc*16];
        #pragma unroll
        for (int ju = 0; ju < 8; ++ju) {
          uint32_t bv = Bu[ju];
          S[2*ju]   += plo(bv) * w;
          S[2*ju+1] += phi(bv) * w;
        }
      }
    }
    __syncthreads();
    #pragma unroll
    for (int j = 0; j < 16; ++j) sB[lG*130 + oc*16 + j] = f2us(S[j]);
    __syncthreads();
    for (int o = tid; o < CHUNK*HEADDIM; o += 512) {
      int l = o >> 6, p = o & 63;
      float yd = 0.f;
      for (int s = 0; s <= l; ++s)
        yd += sW[l*65 + s] * us2f(sX[s*66 + p]);
      float yo = 0.f;
      const uint32_t* Cu = (const uint32_t*)&sC[l * 130];
      const uint32_t* Su = (const uint32_t*)&sB[p * 130];
      for (int u = 0; u < 64; ++u) {
        uint32_t cv = Cu[u], sv = Su[u];
        yo += plo(cv) * plo(sv) + phi(cv) * phi(sv);
      }
      float y = yd + yo * seAc[l];
      yscan[(size_t)(t0 + l) * DINNER + h * HEADDIM + p] = f2us(y);
    }
  }
}

__global__ __launch_bounds__(256) void gate_rmsnorm_dskip(
    const unsigned short* __restrict__ proj, const float* __restrict__ cw,
    const float* __restrict__ cb, const float* __restrict__ Dv,
    const float* __restrict__ norm_w, unsigned short* __restrict__ yscan) {
  const int t = blockIdx.x;
  const int tid = threadIdx.x;
  const int b = t >> 11, lb = t & 2047;
  __shared__ float ybuf[DINNER];
  __shared__ float wpart[4];
  __shared__ float sinv;
  float ss = 0.f;
  for (int i = tid; i < DINNER; i += 256) {
    float zv = us2f(proj[(size_t)t * NPROJ + i]);
    float acc = cb[i];
    #pragma unroll
    for (int j = 0; j < 4; ++j) {
      int ll = lb - 3 + j;
      if (ll >= 0)
        acc += cw[i*4 + j] * us2f(proj[(size_t)(b*SEQ + ll) * NPROJ + DINNER + i]);
    }
    float xh = acc / (1.f + expf(-acc));
    float yv = us2f(yscan[(size_t)t * DINNER + i]) + xh * Dv[i >> 6];
    yv = yv * (zv / (1.f + expf(-zv)));
    ybuf[i] = yv;
    ss += yv * yv;
  }
  #pragma unroll
  for (int off = 32; off > 0; off >>= 1) ss += __shfl_down(ss, off, 64);
  if ((tid & 63) == 0) wpart[tid >> 6] = ss;
  __syncthreads();
  if (tid == 0) {
    float tot = wpart[0] + wpart[1] + wpart[2] + wpart[3];
    sinv = 1.f / sqrtf(tot / (float)DINNER + 1e-5f);
  }
  __syncthreads();
  float inv = sinv;
  for (int i = tid; i < DINNER; i += 256)
    yscan[(size_t)t * DINNER + i] = f2us(ybuf[i] * inv * norm_w[i]);
}

// ---------------- launch ----------------
extern "C" void kernel_launch(void* const* d_in, const int* in_sizes, int n_in,
                              void* d_out, int out_size, void* d_ws, size_t ws_size,
                              hipStream_t stream) {
  const float* x          = (const float*)d_in[0];
  const float* in_proj_w  = (const float*)d_in[1];
  const float* conv_w     = (const float*)d_in[2];
  const float* conv_b     = (const float*)d_in[3];
  const float* A_log      = (const float*)d_in[4];
  const float* Dv         = (const float*)d_in[5];
  const float* dt_bias    = (const float*)d_in[6];
  const float* norm_w     = (const float*)d_in[7];
  const float* out_proj_w = (const float*)d_in[8];
  float* out = (float*)d_out;

  unsigned short* proj  = (unsigned short*)d_ws;
  float*          dtr   = (float*)(proj + (size_t)TOKENS * NPROJ);
  unsigned short* yscan = (unsigned short*)(dtr + (size_t)TOKENS * NHEADS);
  unsigned short* cs    = yscan + (size_t)TOKENS * DINNER;
  float*          acs   = (float*)(cs + (size_t)B_SZ*NHEADS*NCHUNK*HEADDIM*DSTATE);
  unsigned short* bcact = (unsigned short*)(acs + (size_t)B_SZ*NHEADS*NCHUNK*64);
  float*          gbuf  = (float*)(bcact + (size_t)TOKENS*256);
  const size_t NEEDED = (size_t)((char*)(gbuf + (size_t)B_SZ*NCHUNK*4096) - (char*)d_ws);

  unsigned short* xb  = cs;                                  // TOKENS*DMODEL
  unsigned short* wib = xb + (size_t)TOKENS * DMODEL;        // NPROJ*DMODEL
  unsigned short* wob = proj;                                // DMODEL*DINNER

  if (ws_size >= NEEDED) {
    cast_f32_bf16<<<(TOKENS*DMODEL)/1024, 256, 0, stream>>>(x, xb, TOKENS*DMODEL);
    cast_f32_bf16<<<((size_t)NPROJ*DMODEL)/1024, 256, 0, stream>>>(in_proj_w, wib, NPROJ*DMODEL);
    {
      int nwg = (TOKENS/128) * (NPROJ/256);   // 32*33 = 1056, %8 == 0
      gemm_bt_p3<1,128><<<nwg, 256, 0, stream>>>(xb, wib, proj, TOKENS, NPROJ, DMODEL, TOKENS/128);
    }
    dt_gemm<<<TOKENS/64, 256, 0, stream>>>(x, in_proj_w, dtr);
    bc_conv_g<<<B_SZ*NCHUNK, 256, 0, stream>>>(proj, conv_w, conv_b, bcact, gbuf);
    ssd_phase_a2_mfma<<<B_SZ*NCHUNK*NHEADS, 256, 0, stream>>>(
        proj, bcact, dtr, conv_w, conv_b, A_log, dt_bias, gbuf, Dv, cs, acs, yscan);
    ssd_scan_states<<<(B_SZ*NHEADS*HEADDIM*DSTATE)/(256*8), 256, 0, stream>>>(cs, acs);
    ssd_phase_c_mfma<<<B_SZ*NCHUNK*NHEADS, 256, 0, stream>>>(bcact, cs, acs, yscan);
    gate_rmsnorm2<<<TOKENS, 256, 0, stream>>>(proj, norm_w, yscan);
    cast_f32_bf16<<<((size_t)DMODEL*DINNER)/1024, 256, 0, stream>>>(out_proj_w, wob, DMODEL*DINNER);
    {
      int nwg = (TOKENS/64) * (DMODEL/256);   // 64*8 = 512, %8 == 0
      gemm_bt_p3<0,64><<<nwg, 256, 0, stream>>>(yscan, wob, out, TOKENS, DMODEL, DINNER, TOKENS/64);
    }
  } else {
    {
      dim3 grid(NPROJ/128, TOKENS/128);
      gemm_nt<float, unsigned short><<<grid, 256, 0, stream>>>(
          x, in_proj_w, proj, TOKENS, NPROJ, DMODEL);
    }
    dt_gemm<<<TOKENS/64, 256, 0, stream>>>(x, in_proj_w, dtr);
    ssd_fused<<<B_SZ*NHEADS, 512, 0, stream>>>(proj, dtr, conv_w, conv_b,
                                               A_log, dt_bias, yscan);
    gate_rmsnorm_dskip<<<TOKENS, 256, 0, stream>>>(proj, conv_w, conv_b, Dv, norm_w, yscan);
    {
      dim3 grid(DMODEL/128, TOKENS/128);
      gemm_nt<unsigned short, float><<<grid, 256, 0, stream>>>(
          yscan, out_proj_w, out, TOKENS, DMODEL, DINNER);
    }
  }
}